// Round 2
// baseline (405.682 us; speedup 1.0000x reference)
//
#include <hip/hip_runtime.h>

// Problem constants
constexpr int Bn = 32, Ln = 1855, Kn = 7, Tn = 40, CIn = 8, COn = 32, TKSn = 5, TOn = 36;
constexpr int BG   = 8;               // b per block
constexpr int KRED = Kn * TKSn * CIn; // 280
constexpr int KPAD = 288;             // padded K (9 chunks of 32), [280,288) zero
constexpr int WROW = 296;             // fallback kernel's padded wt row
constexpr int XS_ELEMS  = BG * Kn * Tn * CIn; // 17920 bf16
constexpr int XS_STRIDE = XS_ELEMS + 8;       // + zero A-pad row (16B-aligned stride)
constexpr int LPB = 4;                        // l values per block (pipelined)
constexpr int NLB = (Ln + LPB - 1) / LPB;     // 464
constexpr size_t XN = (size_t)Bn * Ln * Tn * CIn; // 18,995,200 elems

// workspace layout (bytes)
constexpr size_t WS_WT   = 0;                 // 32*288 bf16 = 18432 B
constexpr size_t WS_ZPAD = 18432;             // 128 B of zeros (masked-gather target)
constexpr size_t WS_XBF  = 18560;             // XN bf16 = 37,990,400 B
constexpr size_t WS_NEED = WS_XBF + XN * 2;

typedef __attribute__((ext_vector_type(8))) short bf16x8;          // 8 bf16 = 4 VGPRs
typedef __attribute__((ext_vector_type(8))) unsigned short u16x8;
typedef __attribute__((ext_vector_type(4))) float f32x4;           // MFMA C/D

__device__ inline unsigned short f2bf(float f) {
    unsigned u = __builtin_bit_cast(unsigned, f);
    u += 0x7fffu + ((u >> 16) & 1u); // RNE
    return (unsigned short)(u >> 16);
}

__device__ inline void gload_lds16(const void* g, void* lds) {
    __builtin_amdgcn_global_load_lds(
        (const __attribute__((address_space(1))) unsigned int*)g,
        (__attribute__((address_space(3))) unsigned int*)lds,
        16, 0, 0);
}

// ---- prep kernels (run once per launch, tiny) ----

__global__ __launch_bounds__(256) void prep_w(const float* __restrict__ w,
                                              unsigned short* __restrict__ wt,
                                              unsigned short* __restrict__ zpad) {
    const int tid = threadIdx.x;
    for (int p = tid; p < KRED * COn; p += 256) { // 8960
        int o  = p & 31;
        int kr = p >> 5;                          // (k*5+tau)*8+i
        wt[o * KPAD + kr] = f2bf(w[p]);
    }
    for (int p = tid; p < COn * (KPAD - KRED); p += 256) { // 256
        int o = p >> 3;
        wt[o * KPAD + KRED + (p & 7)] = 0;
    }
    if (tid < 64) zpad[tid] = 0; // 128 B zeros
}

__global__ __launch_bounds__(256) void prep_x(const float* __restrict__ x,
                                              unsigned short* __restrict__ xbf) {
    const size_t n8 = XN / 8; // 2,374,400 groups of 8
    for (size_t p = (size_t)blockIdx.x * 256 + threadIdx.x; p < n8;
         p += (size_t)gridDim.x * 256) {
        float4 a = ((const float4*)x)[2 * p];
        float4 b = ((const float4*)x)[2 * p + 1];
        u16x8 v;
        v[0] = f2bf(a.x); v[1] = f2bf(a.y); v[2] = f2bf(a.z); v[3] = f2bf(a.w);
        v[4] = f2bf(b.x); v[5] = f2bf(b.y); v[6] = f2bf(b.z); v[7] = f2bf(b.w);
        *(u16x8*)&xbf[p * 8] = v;
    }
}

// ---- main kernel: pipelined over 4 l per block, double-buffered gather ----
__global__ __launch_bounds__(256, 2) void conv_mfma3(
    const unsigned short* __restrict__ xbf,  // (B, L, T, CIn) bf16
    const int*   __restrict__ nbr,           // (L, K)
    const unsigned short* __restrict__ wt,   // [32][288] bf16
    const unsigned short* __restrict__ zpad, // 128B zeros
    const float* __restrict__ bias,          // (COn,)
    float*       __restrict__ out)           // (B, L, TOn, COn)
{
    // xs[buf]: gathered neighbor rows, bf16, [b_local][k][t][i], i contiguous.
    // +8 zero pad row at XS_ELEMS (A-source for padded K chunk, quad==3, c==8).
    __shared__ unsigned short xs[2][XS_STRIDE]; // 2 x 35,856 B -> 2 blocks/CU

    const int tid  = threadIdx.x;
    const int wave = tid >> 6;
    const int lane = tid & 63;
    const int l0   = blockIdx.x * LPB;
    const int bg   = blockIdx.y;

    if (tid < 8) { xs[0][XS_ELEMS + tid] = 0; xs[1][XS_ELEMS + tid] = 0; }

    // ---- per-lane gather invariants (hoisted out of the l loop) ----
    // chunk ch = wave + 4*s covers ushort8 indices [ch*64, ch*64+64)
    size_t g_off[9]; int g_k[9]; int g_ch[9]; bool g_on[9];
    #pragma unroll
    for (int s = 0; s < 9; ++s) {
        const int ch = wave + 4 * s;
        g_ch[s] = ch;
        g_on[s] = (ch < 35);
        const int chc = g_on[s] ? ch : 0;
        const int p   = chc * 64 + lane;   // [0, 2240) ushort8 units
        const int row = p / 40;            // (b_local, k) row
        const int q   = p - row * 40;      // t index
        const int bl  = row / 7;
        g_k[s]   = row - bl * 7;
        g_off[s] = (size_t)(bg * BG + bl) * Ln * 320 + (size_t)q * 8;
    }

    auto stage = [&](int buf, int ll) {
        const int nb = ll * Kn;
        #pragma unroll
        for (int s = 0; s < 9; ++s) {
            if (g_on[s]) {
                const int l2 = nbr[nb + g_k[s]];
                const unsigned short* src = zpad;
                if (l2 >= 0) src = xbf + g_off[s] + (size_t)l2 * 320;
                gload_lds16(src, &xs[buf][g_ch[s] * 512]);
            }
        }
    };

    // ---- B fragments straight from global (18KB, L2-broadcast) ----
    const int quad = lane >> 4;
    const int lrow = lane & 15;
    const int o_base  = (wave & 1) * 16;  // o col-tile
    const int rt_base = (wave >> 1) * 9;  // 9 row-tiles of 16 per wave

    bf16x8 bfrag[9];
    const unsigned short* wrow = wt + (o_base + lrow) * KPAD;
    #pragma unroll
    for (int c = 0; c < 9; ++c)
        bfrag[c] = *(const bf16x8*)(wrow + c * 32 + quad * 8);
    const float bv = bias[o_base + lrow];

    auto compute_store = [&](int buf, int l) {
        const unsigned short* xp = xs[buf];
        #pragma unroll
        for (int g = 0; g < 3; ++g) {       // 3 groups x 3 row-tiles (ILP)
            const int rt0 = rt_base + g * 3;
            f32x4 acc0 = {0.f,0.f,0.f,0.f}, acc1 = acc0, acc2 = acc0;
            const int m0 = (rt0 + 0) * 16 + lrow;
            const int m1 = (rt0 + 1) * 16 + lrow;
            const int m2 = (rt0 + 2) * 16 + lrow;
            const int bl0 = m0 / 36, t0 = m0 - bl0 * 36;
            const int bl1 = m1 / 36, t1 = m1 - bl1 * 36;
            const int bl2 = m2 / 36, t2 = m2 - bl2 * 36;
            const int base0 = bl0 * 2240 + t0 * 8;
            const int base1 = bl1 * 2240 + t1 * 8;
            const int base2 = bl2 * 2240 + t2 * 8;
            __builtin_amdgcn_s_setprio(1);
            #pragma unroll
            for (int c = 0; c < 9; ++c) {
                const int p = c * 4 + quad;         // (k,tau) pair, 36th is pad
                const int knbr = p / 5, tau = p - knbr * 5;
                const int koff = knbr * 320 + tau * 8;
                int o0 = base0 + koff, o1 = base1 + koff, o2 = base2 + koff;
                if (c == 8 && quad == 3) { o0 = XS_ELEMS; o1 = XS_ELEMS; o2 = XS_ELEMS; }
                bf16x8 a0 = *(const bf16x8*)&xp[o0];
                bf16x8 a1 = *(const bf16x8*)&xp[o1];
                bf16x8 a2 = *(const bf16x8*)&xp[o2];
                acc0 = __builtin_amdgcn_mfma_f32_16x16x32_bf16(a0, bfrag[c], acc0, 0, 0, 0);
                acc1 = __builtin_amdgcn_mfma_f32_16x16x32_bf16(a1, bfrag[c], acc1, 0, 0, 0);
                acc2 = __builtin_amdgcn_mfma_f32_16x16x32_bf16(a2, bfrag[c], acc2, 0, 0, 0);
            }
            __builtin_amdgcn_s_setprio(0);
            // epilogue: C/D layout col=lane&15, row=quad*4+reg  [m89/m91 verified]
            #pragma unroll
            for (int i = 0; i < 3; ++i) {
                const f32x4 acc = (i == 0) ? acc0 : ((i == 1) ? acc1 : acc2);
                const int rt = rt0 + i;
                #pragma unroll
                for (int reg = 0; reg < 4; ++reg) {
                    const int m  = rt * 16 + quad * 4 + reg;
                    const int bl = m / 36, t = m - bl * 36;
                    const size_t off =
                        (((size_t)(bg * BG + bl) * Ln + l) * TOn + t) * COn + o_base + lrow;
                    out[off] = acc[reg] + bv;
                }
            }
        }
    };

    // ---- pipelined l loop: barrier -> prefetch next -> compute current ----
    stage(0, l0); // l0 <= 1852 always valid
    int cur = 0;
    #pragma unroll
    for (int j = 0; j < LPB; ++j) {
        const int l = l0 + j;
        __syncthreads(); // vmcnt(0) drain: buf[cur] gathers (issued one phase ago) done
        if (j + 1 < LPB && l + 1 < Ln) stage(cur ^ 1, l + 1); // issue BEFORE compute
        if (l < Ln) compute_store(cur, l);
        cur ^= 1;
    }
}

// ---- fallback (original kernel) if workspace is too small ----
__global__ __launch_bounds__(256) void conv_mfma(
    const float* __restrict__ x, const int* __restrict__ nbr,
    const float* __restrict__ w, const float* __restrict__ bias,
    float* __restrict__ out)
{
    __shared__ unsigned short xs[XS_ELEMS + 8];
    __shared__ unsigned short wt[COn * WROW];

    const int tid = threadIdx.x;
    const int l   = blockIdx.x;
    const int bg  = blockIdx.y;

    for (int p = tid; p < KRED * COn; p += 256) {
        int o  = p & 31;
        int kr = p >> 5;
        wt[o * WROW + kr] = f2bf(w[p]);
    }
    for (int p = tid; p < COn * (WROW - KRED); p += 256) {
        int o = p >> 4;
        wt[o * WROW + KRED + (p & 15)] = 0;
    }
    if (tid < 8) xs[XS_ELEMS + tid] = 0;

    for (int p = tid; p < BG * Kn * 80; p += 256) {
        int b_local = p / 560;
        int r = p - b_local * 560;
        int k = r / 80;
        int q = r - k * 80;
        int l2 = nbr[l * Kn + k];
        float4 v = make_float4(0.f, 0.f, 0.f, 0.f);
        if (l2 >= 0)
            v = ((const float4*)x)[((size_t)(bg * BG + b_local) * Ln + l2) * 80 + q];
        ushort4 pk;
        pk.x = f2bf(v.x); pk.y = f2bf(v.y); pk.z = f2bf(v.z); pk.w = f2bf(v.w);
        *(ushort4*)&xs[p * 4] = pk;
    }
    __syncthreads();

    const int wave = tid >> 6;
    const int lane = tid & 63;
    const int quad = lane >> 4;
    const int lrow = lane & 15;
    const int o_base  = (wave & 1) * 16;
    const int rt_base = (wave >> 1) * 9;

    bf16x8 bfrag[9];
    #pragma unroll
    for (int c = 0; c < 9; ++c)
        bfrag[c] = *(const bf16x8*)&wt[(o_base + lrow) * WROW + c * 32 + quad * 8];

    const float bv = bias[o_base + lrow];

    #pragma unroll
    for (int g = 0; g < 3; ++g) {
        const int rt0 = rt_base + g * 3;
        f32x4 acc0 = {0.f,0.f,0.f,0.f}, acc1 = acc0, acc2 = acc0;
        const int m0 = (rt0 + 0) * 16 + lrow;
        const int m1 = (rt0 + 1) * 16 + lrow;
        const int m2 = (rt0 + 2) * 16 + lrow;
        const int bl0 = m0 / 36, t0 = m0 - bl0 * 36;
        const int bl1 = m1 / 36, t1 = m1 - bl1 * 36;
        const int bl2 = m2 / 36, t2 = m2 - bl2 * 36;
        const int base0 = bl0 * 2240 + t0 * 8;
        const int base1 = bl1 * 2240 + t1 * 8;
        const int base2 = bl2 * 2240 + t2 * 8;
        #pragma unroll
        for (int c = 0; c < 9; ++c) {
            const int p = c * 4 + quad;
            const int knbr = p / 5, tau = p - knbr * 5;
            const int koff = knbr * 320 + tau * 8;
            int o0 = base0 + koff, o1 = base1 + koff, o2 = base2 + koff;
            if (c == 8 && quad == 3) { o0 = XS_ELEMS; o1 = XS_ELEMS; o2 = XS_ELEMS; }
            bf16x8 a0 = *(const bf16x8*)&xs[o0];
            bf16x8 a1 = *(const bf16x8*)&xs[o1];
            bf16x8 a2 = *(const bf16x8*)&xs[o2];
            acc0 = __builtin_amdgcn_mfma_f32_16x16x32_bf16(a0, bfrag[c], acc0, 0, 0, 0);
            acc1 = __builtin_amdgcn_mfma_f32_16x16x32_bf16(a1, bfrag[c], acc1, 0, 0, 0);
            acc2 = __builtin_amdgcn_mfma_f32_16x16x32_bf16(a2, bfrag[c], acc2, 0, 0, 0);
        }
        #pragma unroll
        for (int i = 0; i < 3; ++i) {
            const f32x4 acc = (i == 0) ? acc0 : ((i == 1) ? acc1 : acc2);
            const int rt = rt0 + i;
            #pragma unroll
            for (int reg = 0; reg < 4; ++reg) {
                const int m  = rt * 16 + quad * 4 + reg;
                const int bl = m / 36, t = m - bl * 36;
                const size_t off =
                    (((size_t)(bg * BG + bl) * Ln + l) * TOn + t) * COn + o_base + lrow;
                out[off] = acc[reg] + bv;
            }
        }
    }
}

extern "C" void kernel_launch(void* const* d_in, const int* in_sizes, int n_in,
                              void* d_out, int out_size, void* d_ws, size_t ws_size,
                              hipStream_t stream) {
    const float* x    = (const float*)d_in[0];
    const int*   nbr  = (const int*)d_in[1];
    const float* w    = (const float*)d_in[2];
    const float* bias = (const float*)d_in[3];
    float*       out  = (float*)d_out;

    if (ws_size >= WS_NEED && d_ws != nullptr) {
        unsigned short* wt   = (unsigned short*)((char*)d_ws + WS_WT);
        unsigned short* zpad = (unsigned short*)((char*)d_ws + WS_ZPAD);
        unsigned short* xbf  = (unsigned short*)((char*)d_ws + WS_XBF);
        prep_w<<<1, 256, 0, stream>>>(w, wt, zpad);
        prep_x<<<2048, 256, 0, stream>>>(x, xbf);
        conv_mfma3<<<dim3(NLB, Bn / BG), dim3(256), 0, stream>>>(xbf, nbr, wt, zpad, bias, out);
    } else {
        conv_mfma<<<dim3(Ln, Bn / BG), dim3(256), 0, stream>>>(x, nbr, w, bias, out);
    }
}

// Round 3
// 369.627 us; speedup vs baseline: 1.0975x; 1.0975x over previous
//
#include <hip/hip_runtime.h>

// Problem constants
constexpr int Bn = 32, Ln = 1855, Kn = 7, Tn = 40, CIn = 8, COn = 32, TKSn = 5, TOn = 36;
constexpr int BG   = 8;               // b per (bg) group
constexpr int KRED = Kn * TKSn * CIn; // 280
constexpr int KPAD = 288;             // padded K (9 chunks of 32), [280,288) zero
constexpr int WROW = 296;             // fallback kernel's padded wt row
constexpr int XS_ELEMS = BG * Kn * Tn * CIn;  // fallback: 17920 bf16
constexpr int XS2 = 4 * Kn * Tn * CIn;        // main: 4 b_local x 7 k x 40 t x 8 i = 8960
constexpr size_t XN = (size_t)Bn * Ln * Tn * CIn; // 18,995,200 elems

// workspace layout (bytes)
constexpr size_t WS_WT   = 0;                 // 32*288 bf16 = 18432 B
constexpr size_t WS_ZPAD = 18432;             // 128 B of zeros (masked-gather target)
constexpr size_t WS_XBF  = 18560;             // XN bf16 = 37,990,400 B
constexpr size_t WS_NEED = WS_XBF + XN * 2;

typedef __attribute__((ext_vector_type(8))) short bf16x8;          // 8 bf16 = 4 VGPRs
typedef __attribute__((ext_vector_type(8))) unsigned short u16x8;
typedef __attribute__((ext_vector_type(4))) float f32x4;           // MFMA C/D

__device__ inline unsigned short f2bf(float f) {
    unsigned u = __builtin_bit_cast(unsigned, f);
    u += 0x7fffu + ((u >> 16) & 1u); // RNE
    return (unsigned short)(u >> 16);
}

__device__ inline void gload_lds16(const void* g, void* lds) {
    __builtin_amdgcn_global_load_lds(
        (const __attribute__((address_space(1))) unsigned int*)g,
        (__attribute__((address_space(3))) unsigned int*)lds,
        16, 0, 0);
}

// ---- prep kernels (run once per launch, tiny) ----

__global__ __launch_bounds__(256) void prep_w(const float* __restrict__ w,
                                              unsigned short* __restrict__ wt,
                                              unsigned short* __restrict__ zpad) {
    const int tid = threadIdx.x;
    for (int p = tid; p < KRED * COn; p += 256) { // 8960
        int o  = p & 31;
        int kr = p >> 5;                          // (k*5+tau)*8+i
        wt[o * KPAD + kr] = f2bf(w[p]);
    }
    for (int p = tid; p < COn * (KPAD - KRED); p += 256) { // 256
        int o = p >> 3;
        wt[o * KPAD + KRED + (p & 7)] = 0;
    }
    if (tid < 64) zpad[tid] = 0; // 128 B zeros
}

__global__ __launch_bounds__(256) void prep_x(const float* __restrict__ x,
                                              unsigned short* __restrict__ xbf) {
    const size_t n8 = XN / 8; // 2,374,400 groups of 8
    for (size_t p = (size_t)blockIdx.x * 256 + threadIdx.x; p < n8;
         p += (size_t)gridDim.x * 256) {
        float4 a = ((const float4*)x)[2 * p];
        float4 b = ((const float4*)x)[2 * p + 1];
        u16x8 v;
        v[0] = f2bf(a.x); v[1] = f2bf(a.y); v[2] = f2bf(a.z); v[3] = f2bf(a.w);
        v[4] = f2bf(b.x); v[5] = f2bf(b.y); v[6] = f2bf(b.z); v[7] = f2bf(b.w);
        *(u16x8*)&xbf[p * 8] = v;
    }
}

// ---- main kernel: 1 wave per block, 144 rows x 32 cols, read-A-once, no barrier ----
__global__ __launch_bounds__(64, 2) void conv_mfma4(
    const unsigned short* __restrict__ xbf,  // (B, L, T, CIn) bf16
    const int*   __restrict__ nbr,           // (L, K)
    const unsigned short* __restrict__ wt,   // [32][288] bf16
    const unsigned short* __restrict__ zpad, // 128B zeros
    const float* __restrict__ bias,          // (COn,)
    float*       __restrict__ out)           // (B, L, TOn, COn)
{
    // xs: 4 b_local x 7 k x 40 t x 8 i (bf16), +8 zero pad row at XS2.
    // 17,936 B -> 8 blocks/CU. Staged and consumed by THIS wave only: no barrier.
    __shared__ unsigned short xs[XS2 + 8];

    const int lane = threadIdx.x;
    const int l    = blockIdx.x;
    const int half = blockIdx.y & 1;      // which 4-batch half
    const int bg   = blockIdx.y >> 1;
    const int b0   = bg * BG + half * 4;  // global b of bl=0

    if (lane < 8) xs[XS2 + lane] = 0;     // zero A-pad row (same-wave lgkm ordering)

    // one nbr line load, redistributed by shfl (removes dependent loads from stage)
    int nv = 0;
    if (lane < Kn) nv = nbr[l * Kn + lane];

    // ---- stage 18 chunks of 1024B via global->LDS (last chunk: 32 lanes) ----
    #pragma unroll
    for (int s = 0; s < 18; ++s) {
        if (s < 17 || lane < 32) {
            const int u   = s * 64 + lane;    // ushort8 unit, [0,1120)
            const int row = u / 40;           // (bl,k) row
            const int q   = u - row * 40;     // t
            const int bl  = row / 7;
            const int k   = row - bl * 7;
            const int l2  = __shfl(nv, k);
            const unsigned short* src = zpad;
            if (l2 >= 0)
                src = xbf + ((size_t)(b0 + bl) * Ln + l2) * 320 + q * 8;
            gload_lds16(src, &xs[s * 512]);
        }
    }

    const int quad = lane >> 4;
    const int lrow = lane & 15;

    // ---- B fragments for BOTH o-halves (18 x bf16x8 = 72 VGPR), from global ----
    bf16x8 bfrag[2][9];
    #pragma unroll
    for (int oh = 0; oh < 2; ++oh)
        #pragma unroll
        for (int c = 0; c < 9; ++c)
            bfrag[oh][c] = *(const bf16x8*)(wt + (oh * 16 + lrow) * KPAD + c * 32 + quad * 8);
    const float bv0 = bias[lrow];
    const float bv1 = bias[16 + lrow];

    // Drain staging (and bfrag) before any ds_read. ds_read is a memory op,
    // so the "memory" clobber orders it after this wait (rule 18 caveat n/a).
    asm volatile("s_waitcnt vmcnt(0)" ::: "memory");

    // ---- compute: 9 row-tiles of 16 x 32 cols; each A-read feeds 2 MFMAs ----
    #pragma unroll
    for (int g = 0; g < 3; ++g) {
        const int rt0 = g * 3;
        f32x4 a00 = {0.f,0.f,0.f,0.f};
        f32x4 acc00 = a00, acc01 = a00, acc10 = a00, acc11 = a00, acc20 = a00, acc21 = a00;
        const int m0 = (rt0 + 0) * 16 + lrow;
        const int m1 = (rt0 + 1) * 16 + lrow;
        const int m2 = (rt0 + 2) * 16 + lrow;
        const int bl0 = m0 / 36, t0 = m0 - bl0 * 36;
        const int bl1 = m1 / 36, t1 = m1 - bl1 * 36;
        const int bl2 = m2 / 36, t2 = m2 - bl2 * 36;
        const int base0 = bl0 * 2240 + t0 * 8;
        const int base1 = bl1 * 2240 + t1 * 8;
        const int base2 = bl2 * 2240 + t2 * 8;
        __builtin_amdgcn_s_setprio(1);
        #pragma unroll
        for (int c = 0; c < 9; ++c) {
            const int p = c * 4 + quad;         // (k,tau) pair, 36th is pad
            const int knbr = p / 5, tau = p - knbr * 5;
            const int koff = knbr * 320 + tau * 8;
            int o0 = base0 + koff, o1 = base1 + koff, o2 = base2 + koff;
            if (c == 8 && quad == 3) { o0 = XS2; o1 = XS2; o2 = XS2; }
            bf16x8 a0 = *(const bf16x8*)&xs[o0];
            bf16x8 a1 = *(const bf16x8*)&xs[o1];
            bf16x8 a2 = *(const bf16x8*)&xs[o2];
            acc00 = __builtin_amdgcn_mfma_f32_16x16x32_bf16(a0, bfrag[0][c], acc00, 0, 0, 0);
            acc01 = __builtin_amdgcn_mfma_f32_16x16x32_bf16(a0, bfrag[1][c], acc01, 0, 0, 0);
            acc10 = __builtin_amdgcn_mfma_f32_16x16x32_bf16(a1, bfrag[0][c], acc10, 0, 0, 0);
            acc11 = __builtin_amdgcn_mfma_f32_16x16x32_bf16(a1, bfrag[1][c], acc11, 0, 0, 0);
            acc20 = __builtin_amdgcn_mfma_f32_16x16x32_bf16(a2, bfrag[0][c], acc20, 0, 0, 0);
            acc21 = __builtin_amdgcn_mfma_f32_16x16x32_bf16(a2, bfrag[1][c], acc21, 0, 0, 0);
        }
        __builtin_amdgcn_s_setprio(0);
        // epilogue: C/D layout col=lane&15, row=quad*4+reg  [m89/m91 verified]
        #pragma unroll
        for (int i = 0; i < 3; ++i) {
            const f32x4 c0 = (i == 0) ? acc00 : ((i == 1) ? acc10 : acc20);
            const f32x4 c1 = (i == 0) ? acc01 : ((i == 1) ? acc11 : acc21);
            const int rt = rt0 + i;
            #pragma unroll
            for (int reg = 0; reg < 4; ++reg) {
                const int m  = rt * 16 + quad * 4 + reg;
                const int bl = m / 36, t = m - bl * 36;
                const size_t off =
                    (((size_t)(b0 + bl) * Ln + l) * TOn + t) * COn + lrow;
                __builtin_nontemporal_store(c0[reg] + bv0, &out[off]);
                __builtin_nontemporal_store(c1[reg] + bv1, &out[off + 16]);
            }
        }
    }
}

// ---- fallback (original kernel) if workspace is too small ----
__global__ __launch_bounds__(256) void conv_mfma(
    const float* __restrict__ x, const int* __restrict__ nbr,
    const float* __restrict__ w, const float* __restrict__ bias,
    float* __restrict__ out)
{
    __shared__ unsigned short xs[XS_ELEMS + 8];
    __shared__ unsigned short wt[COn * WROW];

    const int tid = threadIdx.x;
    const int l   = blockIdx.x;
    const int bg  = blockIdx.y;

    for (int p = tid; p < KRED * COn; p += 256) {
        int o  = p & 31;
        int kr = p >> 5;
        wt[o * WROW + kr] = f2bf(w[p]);
    }
    for (int p = tid; p < COn * (WROW - KRED); p += 256) {
        int o = p >> 4;
        wt[o * WROW + KRED + (p & 15)] = 0;
    }
    if (tid < 8) xs[XS_ELEMS + tid] = 0;

    for (int p = tid; p < BG * Kn * 80; p += 256) {
        int b_local = p / 560;
        int r = p - b_local * 560;
        int k = r / 80;
        int q = r - k * 80;
        int l2 = nbr[l * Kn + k];
        float4 v = make_float4(0.f, 0.f, 0.f, 0.f);
        if (l2 >= 0)
            v = ((const float4*)x)[((size_t)(bg * BG + b_local) * Ln + l2) * 80 + q];
        ushort4 pk;
        pk.x = f2bf(v.x); pk.y = f2bf(v.y); pk.z = f2bf(v.z); pk.w = f2bf(v.w);
        *(ushort4*)&xs[p * 4] = pk;
    }
    __syncthreads();

    const int wave = tid >> 6;
    const int lane = tid & 63;
    const int quad = lane >> 4;
    const int lrow = lane & 15;
    const int o_base  = (wave & 1) * 16;
    const int rt_base = (wave >> 1) * 9;

    bf16x8 bfrag[9];
    #pragma unroll
    for (int c = 0; c < 9; ++c)
        bfrag[c] = *(const bf16x8*)&wt[(o_base + lrow) * WROW + c * 32 + quad * 8];

    const float bv = bias[o_base + lrow];

    #pragma unroll
    for (int g = 0; g < 3; ++g) {
        const int rt0 = rt_base + g * 3;
        f32x4 acc0 = {0.f,0.f,0.f,0.f}, acc1 = acc0, acc2 = acc0;
        const int m0 = (rt0 + 0) * 16 + lrow;
        const int m1 = (rt0 + 1) * 16 + lrow;
        const int m2 = (rt0 + 2) * 16 + lrow;
        const int bl0 = m0 / 36, t0 = m0 - bl0 * 36;
        const int bl1 = m1 / 36, t1 = m1 - bl1 * 36;
        const int bl2 = m2 / 36, t2 = m2 - bl2 * 36;
        const int base0 = bl0 * 2240 + t0 * 8;
        const int base1 = bl1 * 2240 + t1 * 8;
        const int base2 = bl2 * 2240 + t2 * 8;
        #pragma unroll
        for (int c = 0; c < 9; ++c) {
            const int p = c * 4 + quad;
            const int knbr = p / 5, tau = p - knbr * 5;
            const int koff = knbr * 320 + tau * 8;
            int o0 = base0 + koff, o1 = base1 + koff, o2 = base2 + koff;
            if (c == 8 && quad == 3) { o0 = XS_ELEMS; o1 = XS_ELEMS; o2 = XS_ELEMS; }
            bf16x8 a0 = *(const bf16x8*)&xs[o0];
            bf16x8 a1 = *(const bf16x8*)&xs[o1];
            bf16x8 a2 = *(const bf16x8*)&xs[o2];
            acc0 = __builtin_amdgcn_mfma_f32_16x16x32_bf16(a0, bfrag[c], acc0, 0, 0, 0);
            acc1 = __builtin_amdgcn_mfma_f32_16x16x32_bf16(a1, bfrag[c], acc1, 0, 0, 0);
            acc2 = __builtin_amdgcn_mfma_f32_16x16x32_bf16(a2, bfrag[c], acc2, 0, 0, 0);
        }
        #pragma unroll
        for (int i = 0; i < 3; ++i) {
            const f32x4 acc = (i == 0) ? acc0 : ((i == 1) ? acc1 : acc2);
            const int rt = rt0 + i;
            #pragma unroll
            for (int reg = 0; reg < 4; ++reg) {
                const int m  = rt * 16 + quad * 4 + reg;
                const int bl = m / 36, t = m - bl * 36;
                const size_t off =
                    (((size_t)(bg * BG + bl) * Ln + l) * TOn + t) * COn + o_base + lrow;
                out[off] = acc[reg] + bv;
            }
        }
    }
}

extern "C" void kernel_launch(void* const* d_in, const int* in_sizes, int n_in,
                              void* d_out, int out_size, void* d_ws, size_t ws_size,
                              hipStream_t stream) {
    const float* x    = (const float*)d_in[0];
    const int*   nbr  = (const int*)d_in[1];
    const float* w    = (const float*)d_in[2];
    const float* bias = (const float*)d_in[3];
    float*       out  = (float*)d_out;

    if (ws_size >= WS_NEED && d_ws != nullptr) {
        unsigned short* wt   = (unsigned short*)((char*)d_ws + WS_WT);
        unsigned short* zpad = (unsigned short*)((char*)d_ws + WS_ZPAD);
        unsigned short* xbf  = (unsigned short*)((char*)d_ws + WS_XBF);
        prep_w<<<1, 256, 0, stream>>>(w, wt, zpad);
        prep_x<<<2048, 256, 0, stream>>>(x, xbf);
        // 1 wave per block: y = bg(4) x half(2)
        conv_mfma4<<<dim3(Ln, 8), dim3(64), 0, stream>>>(xbf, nbr, wt, zpad, bias, out);
    } else {
        conv_mfma<<<dim3(Ln, Bn / BG), dim3(256), 0, stream>>>(x, nbr, w, bias, out);
    }
}